// Round 13
// baseline (105.154 us; speedup 1.0000x reference)
//
#include <hip/hip_runtime.h>

// VDR (Student-t kernel MMD variance) — fused, no K materialization.
// sum((K-rm-cm+t)^2) == sum(K^2) - sum(rowsum^2)/n - sum(colsum^2)/m + T^2/(mn)
// R1: killed S2 atomic. R2: killed all atomics. R3: tri symmetry.
// R7: fragment-contiguous H -> dense loads. R8/R10/R12: neutral.
// R11 probes: epilogue standalone 1.8us @7-8 waves/SIMD; staging+MFMA ~12-18us
// @7-8 waves/SIMD; fused ~38us @4-5 waves/SIMD. Surviving theory: each phase
// hides its latency only at high TLP; fused never exceeded 5 waves w/o spill
// (R6's occupancy test was spill-corrupted). R13: occupancy WITHOUT spill —
// launch_bounds(256,6) (VGPR<=85) + low-liveness epilogue (e[4] groups, not
// e[16]; TLP replaces ILP). MFMA-phase peak ~72 regs -> no spill expected.
// Tripwire: WRITE_SIZE must stay ~2.1MB; if it balloons, spill -> void.

typedef __attribute__((ext_vector_type(8))) _Float16 f16x8;
typedef __attribute__((ext_vector_type(4))) float f32x4;

#define LOG2G (-0.99304426f)  // log2(gamma(0.8)/(gamma(0.3)*sqrt(0.6)))
#define GAMMA_F 0.50241665f
#define NTILES 8256           // 2080 XX-tri + 4096 XY + 2080 YY (64x64 tiles)
#define SLAB (64 * 4096)

// workspace layout (bytes)
#define OFF_SQ1   0                       // float sq1[4096]
#define OFF_SQ2   16384                   // float sq2[4096]
#define OFF_H1    32768                   // _Float16 H1f[256][16][16][8]
#define OFF_H2    1081344                 // _Float16 H2f[256][16][16][8]
#define OFF_SLABS 2129920                 // float slabs[4][64][4096] {XX, XYr, XYc, YY}
#define OFF_BPART (2129920 + 4194304)     // float bpart[8256]
#define OFF_PARTA (OFF_BPART + 33024)     // double partA[4][16][2]

// ---- prep: fp32 -> f16, fragment-contiguous layout + squared row norms ----
__global__ __launch_bounds__(256) void vdr_prep(const float* __restrict__ X1,
                                                const float* __restrict__ X2,
                                                _Float16* __restrict__ H1,
                                                _Float16* __restrict__ H2,
                                                float* __restrict__ sq1,
                                                float* __restrict__ sq2) {
  const int tid = threadIdx.x;
  const int g = tid & 15;
  const int grow = blockIdx.x * 16 + (tid >> 4);   // 0..8191
  const float* X; _Float16* Hf; float* SQ; int row;
  if (grow < 4096) { X = X1; Hf = H1; SQ = sq1; row = grow; }
  else             { X = X2; Hf = H2; SQ = sq2; row = grow - 4096; }
  const float4* src = reinterpret_cast<const float4*>(X + (size_t)row * 128 + g * 8);
  const float4 v0 = src[0];
  const float4 v1 = src[1];
  f16x8 h;
  h[0] = (_Float16)v0.x; h[1] = (_Float16)v0.y; h[2] = (_Float16)v0.z; h[3] = (_Float16)v0.w;
  h[4] = (_Float16)v1.x; h[5] = (_Float16)v1.y; h[6] = (_Float16)v1.z; h[7] = (_Float16)v1.w;
  const int R = row >> 4;
  reinterpret_cast<f16x8*>(Hf)[(size_t)(R * 16 + g) * 16 + (row & 15)] = h;
  float s = v0.x * v0.x + v0.y * v0.y + v0.z * v0.z + v0.w * v0.w
          + v1.x * v1.x + v1.y * v1.y + v1.z * v1.z + v1.w * v1.w;
  #pragma unroll
  for (int o = 1; o < 16; o <<= 1) s += __shfl_xor(s, o);
  if (g == 0) SQ[row] = s;
}

// upper-triangle 64x64-tile decode: u in [0,2080) -> (bi, bj), bi<=bj
__device__ __forceinline__ void tri_decode(int u, int& bi, int& bj) {
  int b = (int)(64.5f - sqrtf(4160.25f - 2.0f * (float)u));
  if (b < 0) b = 0; if (b > 63) b = 63;
  while (b > 0 && (b * (129 - b)) / 2 > u) --b;
  while (b < 63 && ((b + 1) * (128 - b)) / 2 <= u) ++b;
  bi = b;
  bj = b + (u - (b * (129 - b)) / 2);
}

// ---- tile worker: two sequential 32x64 halves; LOW-LIVENESS epilogue ----
template<bool DG>
__device__ __forceinline__ void work_tile(const f16x8* __restrict__ Af,
                                          const f16x8* __restrict__ Bf,
                                          const float* __restrict__ as,
                                          const float* cb, int bi, int bj,
                                          int lane, int lr, int lg,
                                          float (*rs_area)[65],
                                          float* cpart, float& k2a, float& k2b) {
  for (int h = 0; h < 2; ++h) {
    f32x4 acc[2][4];
    #pragma unroll
    for (int mi = 0; mi < 2; ++mi)
      #pragma unroll
      for (int ni = 0; ni < 4; ++ni)
        acc[mi][ni] = (f32x4){0.f, 0.f, 0.f, 0.f};

    // MFMA phase for rows [h*32, h*32+32)
    #pragma unroll
    for (int ks = 0; ks < 4; ++ks) {
      const int fo = ks * 64 + lane;
      f16x8 a[2], b[4];
      #pragma unroll
      for (int mi = 0; mi < 2; ++mi)
        a[mi] = Af[(size_t)(bi * 4 + h * 2 + mi) * 256 + fo];
      #pragma unroll
      for (int ni = 0; ni < 4; ++ni)
        b[ni] = Bf[(size_t)(bj * 4 + ni) * 256 + fo];
      #pragma unroll
      for (int mi = 0; mi < 2; ++mi)
        #pragma unroll
        for (int ni = 0; ni < 4; ++ni)
          acc[mi][ni] = __builtin_amdgcn_mfma_f32_16x16x32_f16(a[mi], b[ni], acc[mi][ni], 0, 0, 0);
    }

    // epilogue for this half: 4-entry groups, minimal liveness
    #pragma unroll
    for (int mi = 0; mi < 2; ++mi) {
      const int rowb = h * 32 + mi * 16;
      const float4 aq = *reinterpret_cast<const float4*>(as + bi * 64 + rowb + lg * 4);
      const float aqv[4] = {aq.x, aq.y, aq.z, aq.w};
      #pragma unroll
      for (int rg = 0; rg < 4; ++rg) {
        const float pre = __builtin_fmaf(0.5f, aqv[rg], 1.0f);
        float e[4];
        #pragma unroll
        for (int ni = 0; ni < 4; ++ni)
          e[ni] = (pre + cb[ni]) - acc[mi][ni][rg];
        #pragma unroll
        for (int ni = 0; ni < 4; ++ni)
          e[ni] = __builtin_amdgcn_logf(e[ni]);
        #pragma unroll
        for (int ni = 0; ni < 4; ++ni)
          e[ni] = __builtin_amdgcn_exp2f(__builtin_fmaf(-0.8f, e[ni], LOG2G));
        if (DG) {
          #pragma unroll
          for (int ni = 0; ni < 4; ++ni)
            if ((rowb + lg * 4 + rg) == (ni * 16 + lr)) e[ni] = GAMMA_F;
        }
        rs_area[lr][rowb + lg * 4 + rg] = (e[0] + e[1]) + (e[2] + e[3]);
        #pragma unroll
        for (int ni = 0; ni < 4; ++ni)
          cpart[ni] += e[ni];
        k2a = __builtin_fmaf(e[0], e[0], __builtin_fmaf(e[1], e[1], k2a));
        k2b = __builtin_fmaf(e[2], e[2], __builtin_fmaf(e[3], e[3], k2b));
      }
    }
    __builtin_amdgcn_sched_barrier(0);   // keep halves apart (pressure cap)
  }
}

// ---- main: one 64x64 tile per WAVE; 6 waves/SIMD pinned; no barriers ----
__global__ __launch_bounds__(256, 6) void vdr_main(const _Float16* __restrict__ H1,
                                                   const _Float16* __restrict__ H2,
                                                   const float* __restrict__ sq1,
                                                   const float* __restrict__ sq2,
                                                   float* __restrict__ slabs,
                                                   float* __restrict__ bpart) {
  const int w = threadIdx.x >> 6, lane = threadIdx.x & 63;
  const int lr = lane & 15, lg = lane >> 4;
  const int t = blockIdx.x * 4 + w;

  __shared__ float rs_area_s[4][16][65];   // wave-private transpose area
  __shared__ float colbuf_s[4][64];        // wave-private col gather
  float (*rs_area)[65] = rs_area_s[w];
  float* colbuf = colbuf_s[w];

  int z, bi, bj; const _Float16 *A, *B; const float *as, *bs;
  if (t < 2080)      { z = 0; tri_decode(t, bi, bj);        A = H1; B = H1; as = sq1; bs = sq1; }
  else if (t < 6176) { z = 1; int v = t - 2080; bi = v >> 6; bj = v & 63;
                                                            A = H1; B = H2; as = sq1; bs = sq2; }
  else               { z = 2; tri_decode(t - 6176, bi, bj); A = H2; B = H2; as = sq2; bs = sq2; }

  const f16x8* Af = reinterpret_cast<const f16x8*>(A);
  const f16x8* Bf = reinterpret_cast<const f16x8*>(B);

  float cb[4];
  #pragma unroll
  for (int ni = 0; ni < 4; ++ni) cb[ni] = 0.5f * bs[bj * 64 + ni * 16 + lr];

  float cpart[4] = {0.f, 0.f, 0.f, 0.f};
  float k2a = 0.f, k2b = 0.f;

  if ((z != 1) && (bi == bj))
    work_tile<true >(Af, Bf, as, cb, bi, bj, lane, lr, lg, rs_area, cpart, k2a, k2b);
  else
    work_tile<false>(Af, Bf, as, cb, bi, bj, lane, lr, lg, rs_area, cpart, k2a, k2b);

  float rsum = 0.f;
  #pragma unroll
  for (int j = 0; j < 16; ++j) rsum += rs_area[j][lane];   // conflict-free reads

  #pragma unroll
  for (int ni = 0; ni < 4; ++ni) {
    float cp = cpart[ni];
    cp += __shfl_xor(cp, 16);
    cp += __shfl_xor(cp, 32);
    if (lg == 0) colbuf[ni * 16 + lr] = cp;
  }
  const float cval = colbuf[lane];

  float* rowslab = slabs + (size_t)((z == 0) ? 0 : (z == 1) ? 1 : 3) * SLAB;
  rowslab[(size_t)bj * 4096 + bi * 64 + lane] = rsum;
  if (z == 1)
    slabs[(size_t)2 * SLAB + (size_t)bi * 4096 + bj * 64 + lane] = cval;
  else if (bi != bj)
    rowslab[(size_t)bi * 4096 + bj * 64 + lane] = cval;   // mirror (symmetry)

  float k2s = k2a + k2b;
  #pragma unroll
  for (int o = 32; o; o >>= 1) k2s += __shfl_xor(k2s, o);
  if (lane == 0) {
    const float wt = (z != 1 && bi != bj) ? 2.f : 1.f;
    bpart[t] = wt * k2s;
  }
}

// ---- stage A: per (chunk, slab) reduce: sum 64 slot-slabs, emit {sum^2, sum} ----
__global__ __launch_bounds__(256) void vdr_reduceA(const float* __restrict__ slabs,
                                                   double* __restrict__ partA) {
  const int j = blockIdx.y, tid = threadIdx.x;
  const int e = blockIdx.x * 256 + tid;
  const float* base = slabs + (size_t)j * SLAB + e;
  double s = 0.0;
  #pragma unroll
  for (int k = 0; k < 64; ++k) s += (double)base[(size_t)k * 4096];
  double sq = s * s, sm = s;
  #pragma unroll
  for (int o = 32; o; o >>= 1) { sq += __shfl_down(sq, o); sm += __shfl_down(sm, o); }
  __shared__ double sh[4][2];
  const int lane = tid & 63, wid = tid >> 6;
  if (lane == 0) { sh[wid][0] = sq; sh[wid][1] = sm; }
  __syncthreads();
  if (tid == 0) {
    partA[(size_t)(j * 16 + blockIdx.x) * 2 + 0] = sh[0][0] + sh[1][0] + sh[2][0] + sh[3][0];
    partA[(size_t)(j * 16 + blockIdx.x) * 2 + 1] = sh[0][1] + sh[1][1] + sh[2][1] + sh[3][1];
  }
}

// ---- stage B: combine partials + bpart, apply unbiased formula ----
__global__ __launch_bounds__(256) void vdr_reduceB(const double* __restrict__ partA,
                                                   const float* __restrict__ bpart,
                                                   float* __restrict__ out) {
  const int tid = threadIdx.x;
  __shared__ double ssq[4], ssum[4], s2sh[4][3];
  double s2[3] = {0.0, 0.0, 0.0};
  for (int i = tid; i < NTILES; i += 256) {
    const double v = (double)bpart[i];
    if (i < 2080) s2[0] += v; else if (i < 6176) s2[1] += v; else s2[2] += v;
  }
  #pragma unroll
  for (int o = 32; o; o >>= 1) {
    s2[0] += __shfl_down(s2[0], o);
    s2[1] += __shfl_down(s2[1], o);
    s2[2] += __shfl_down(s2[2], o);
  }
  const int lane = tid & 63, wid = tid >> 6;
  if (lane == 0) { s2sh[wid][0] = s2[0]; s2sh[wid][1] = s2[1]; s2sh[wid][2] = s2[2]; }
  if (tid < 64) {
    const int j = tid >> 4, c = tid & 15;
    double sq = partA[(size_t)(j * 16 + c) * 2 + 0];
    double sm = partA[(size_t)(j * 16 + c) * 2 + 1];
    #pragma unroll
    for (int o = 8; o; o >>= 1) { sq += __shfl_down(sq, o, 16); sm += __shfl_down(sm, o, 16); }
    if (c == 0) { ssq[j] = sq; ssum[j] = sm; }
  }
  __syncthreads();
  if (tid == 0) {
    const double S2XX = s2sh[0][0] + s2sh[1][0] + s2sh[2][0] + s2sh[3][0];
    const double S2XY = s2sh[0][1] + s2sh[1][1] + s2sh[2][1] + s2sh[3][1];
    const double S2YY = s2sh[0][2] + s2sh[1][2] + s2sh[2][2] + s2sh[3][2];
    const double inv = 1.0 / 4096.0;
    const double r0 = S2XX - 2.0 * ssq[0] * inv + ssum[0] * ssum[0] * inv * inv;
    const double r1 = S2XY - ssq[1] * inv - ssq[2] * inv + ssum[1] * ssum[1] * inv * inv;
    const double r2 = S2YY - 2.0 * ssq[3] * inv + ssum[3] * ssum[3] * inv * inv;
    const double mf = 4096.0;
    out[0] = (float)((r0 - mf) / ((mf - 1.0) * mf)
                   + (r2 - mf) / ((mf - 1.0) * mf)
                   - 2.0 * r1 / (mf * mf));
  }
}

extern "C" void kernel_launch(void* const* d_in, const int* in_sizes, int n_in,
                              void* d_out, int out_size, void* d_ws, size_t ws_size,
                              hipStream_t stream) {
  const float* X1 = (const float*)d_in[0];
  const float* X2 = (const float*)d_in[1];
  char* ws = (char*)d_ws;
  float* sq1      = (float*)(ws + OFF_SQ1);
  float* sq2      = (float*)(ws + OFF_SQ2);
  _Float16* H1    = (_Float16*)(ws + OFF_H1);
  _Float16* H2    = (_Float16*)(ws + OFF_H2);
  float* slabs    = (float*)(ws + OFF_SLABS);
  float* bpart    = (float*)(ws + OFF_BPART);
  double* partA   = (double*)(ws + OFF_PARTA);

  vdr_prep<<<512, 256, 0, stream>>>(X1, X2, H1, H2, sq1, sq2);
  vdr_main<<<2064, 256, 0, stream>>>(H1, H2, sq1, sq2, slabs, bpart);
  dim3 ga(16, 4);
  vdr_reduceA<<<ga, 256, 0, stream>>>(slabs, partA);
  vdr_reduceB<<<1, 256, 0, stream>>>(partA, bpart, (float*)d_out);
}

// Round 14
// 47.626 us; speedup vs baseline: 2.2079x; 2.2079x over previous
//
#include <hip/hip_runtime.h>

// VDR (Student-t kernel MMD variance) — fused, no K materialization.
// sum((K-rm-cm+t)^2) == sum(K^2) - sum(rowsum^2)/n - sum(colsum^2)/m + T^2/(mn)
// R1: killed S2 atomic. R2: killed all atomics. R3: tri symmetry.
// R7: fragment-contiguous H -> dense loads. R8/R10/R12 neutral. R13: forced
// launch_bounds -> allocator overshoot (40 VGPR + 215MB spill) = VOID; never
// coerce. Model: phases run clean at 7-8 waves/SIMD (probes: epi 1.8us,
// stage+MFMA 11.7us), 3x dirty at <=5 (fused 38us @88 VGPR).
// R14: QUARTER-CHUNK tile (4 x 16x64) -> MFMA-region liveness acc[4]+a[1]+b[4]
// ~= 36 regs, natural total ~65-72 VGPR -> 7 waves/SIMD without coercion.
// B-frags reloaded per chunk (L1-hot). sched_barrier removed. setprio on MFMA.

typedef __attribute__((ext_vector_type(8))) _Float16 f16x8;
typedef __attribute__((ext_vector_type(4))) float f32x4;

#define LOG2G (-0.99304426f)  // log2(gamma(0.8)/(gamma(0.3)*sqrt(0.6)))
#define GAMMA_F 0.50241665f
#define NTILES 8256           // 2080 XX-tri + 4096 XY + 2080 YY (64x64 tiles)
#define SLAB (64 * 4096)

// workspace layout (bytes)
#define OFF_SQ1   0                       // float sq1[4096]
#define OFF_SQ2   16384                   // float sq2[4096]
#define OFF_H1    32768                   // _Float16 H1f[256][16][16][8]
#define OFF_H2    1081344                 // _Float16 H2f[256][16][16][8]
#define OFF_SLABS 2129920                 // float slabs[4][64][4096] {XX, XYr, XYc, YY}
#define OFF_BPART (2129920 + 4194304)     // float bpart[8256]
#define OFF_PARTA (OFF_BPART + 33024)     // double partA[4][16][2]

// ---- prep: fp32 -> f16, fragment-contiguous layout + squared row norms ----
__global__ __launch_bounds__(256) void vdr_prep(const float* __restrict__ X1,
                                                const float* __restrict__ X2,
                                                _Float16* __restrict__ H1,
                                                _Float16* __restrict__ H2,
                                                float* __restrict__ sq1,
                                                float* __restrict__ sq2) {
  const int tid = threadIdx.x;
  const int g = tid & 15;
  const int grow = blockIdx.x * 16 + (tid >> 4);   // 0..8191
  const float* X; _Float16* Hf; float* SQ; int row;
  if (grow < 4096) { X = X1; Hf = H1; SQ = sq1; row = grow; }
  else             { X = X2; Hf = H2; SQ = sq2; row = grow - 4096; }
  const float4* src = reinterpret_cast<const float4*>(X + (size_t)row * 128 + g * 8);
  const float4 v0 = src[0];
  const float4 v1 = src[1];
  f16x8 h;
  h[0] = (_Float16)v0.x; h[1] = (_Float16)v0.y; h[2] = (_Float16)v0.z; h[3] = (_Float16)v0.w;
  h[4] = (_Float16)v1.x; h[5] = (_Float16)v1.y; h[6] = (_Float16)v1.z; h[7] = (_Float16)v1.w;
  const int R = row >> 4;
  reinterpret_cast<f16x8*>(Hf)[(size_t)(R * 16 + g) * 16 + (row & 15)] = h;
  float s = v0.x * v0.x + v0.y * v0.y + v0.z * v0.z + v0.w * v0.w
          + v1.x * v1.x + v1.y * v1.y + v1.z * v1.z + v1.w * v1.w;
  #pragma unroll
  for (int o = 1; o < 16; o <<= 1) s += __shfl_xor(s, o);
  if (g == 0) SQ[row] = s;
}

// upper-triangle 64x64-tile decode: u in [0,2080) -> (bi, bj), bi<=bj
__device__ __forceinline__ void tri_decode(int u, int& bi, int& bj) {
  int b = (int)(64.5f - sqrtf(4160.25f - 2.0f * (float)u));
  if (b < 0) b = 0; if (b > 63) b = 63;
  while (b > 0 && (b * (129 - b)) / 2 > u) --b;
  while (b < 63 && ((b + 1) * (128 - b)) / 2 <= u) ++b;
  bi = b;
  bj = b + (u - (b * (129 - b)) / 2);
}

// ---- tile worker: four sequential 16x64 chunks; minimal liveness ----
template<bool DG>
__device__ __forceinline__ void work_tile(const f16x8* __restrict__ Af,
                                          const f16x8* __restrict__ Bf,
                                          const float* __restrict__ as,
                                          const float* cb, int bi, int bj,
                                          int lane, int lr, int lg,
                                          float (*rs_area)[65],
                                          float* cpart, float& k2a, float& k2b) {
  for (int q = 0; q < 4; ++q) {
    f32x4 acc[4];
    #pragma unroll
    for (int ni = 0; ni < 4; ++ni)
      acc[ni] = (f32x4){0.f, 0.f, 0.f, 0.f};

    // MFMA phase for rows [q*16, q*16+16): per ks only a[1]+b[4] frags live
    __builtin_amdgcn_s_setprio(1);
    #pragma unroll
    for (int ks = 0; ks < 4; ++ks) {
      const int fo = ks * 64 + lane;
      const f16x8 a = Af[(size_t)(bi * 4 + q) * 256 + fo];
      f16x8 b[4];
      #pragma unroll
      for (int ni = 0; ni < 4; ++ni)
        b[ni] = Bf[(size_t)(bj * 4 + ni) * 256 + fo];
      #pragma unroll
      for (int ni = 0; ni < 4; ++ni)
        acc[ni] = __builtin_amdgcn_mfma_f32_16x16x32_f16(a, b[ni], acc[ni], 0, 0, 0);
    }
    __builtin_amdgcn_s_setprio(0);

    // epilogue for this chunk (acc dies here)
    const int rowb = q * 16;
    const float4 aq = *reinterpret_cast<const float4*>(as + bi * 64 + rowb + lg * 4);
    const float aqv[4] = {aq.x, aq.y, aq.z, aq.w};
    #pragma unroll
    for (int rg = 0; rg < 4; ++rg) {
      const float pre = __builtin_fmaf(0.5f, aqv[rg], 1.0f);
      float e[4];
      #pragma unroll
      for (int ni = 0; ni < 4; ++ni)
        e[ni] = (pre + cb[ni]) - acc[ni][rg];
      #pragma unroll
      for (int ni = 0; ni < 4; ++ni)
        e[ni] = __builtin_amdgcn_logf(e[ni]);
      #pragma unroll
      for (int ni = 0; ni < 4; ++ni)
        e[ni] = __builtin_amdgcn_exp2f(__builtin_fmaf(-0.8f, e[ni], LOG2G));
      if (DG) {
        #pragma unroll
        for (int ni = 0; ni < 4; ++ni)
          if ((rowb + lg * 4 + rg) == (ni * 16 + lr)) e[ni] = GAMMA_F;
      }
      rs_area[lr][rowb + lg * 4 + rg] = (e[0] + e[1]) + (e[2] + e[3]);
      #pragma unroll
      for (int ni = 0; ni < 4; ++ni)
        cpart[ni] += e[ni];
      k2a = __builtin_fmaf(e[0], e[0], __builtin_fmaf(e[1], e[1], k2a));
      k2b = __builtin_fmaf(e[2], e[2], __builtin_fmaf(e[3], e[3], k2b));
    }
  }
}

// ---- main: one 64x64 tile per WAVE; no barriers; low natural VGPR ----
__global__ __launch_bounds__(256) void vdr_main(const _Float16* __restrict__ H1,
                                                const _Float16* __restrict__ H2,
                                                const float* __restrict__ sq1,
                                                const float* __restrict__ sq2,
                                                float* __restrict__ slabs,
                                                float* __restrict__ bpart) {
  const int w = threadIdx.x >> 6, lane = threadIdx.x & 63;
  const int lr = lane & 15, lg = lane >> 4;
  const int t = blockIdx.x * 4 + w;

  __shared__ float rs_area_s[4][16][65];   // wave-private transpose area
  __shared__ float colbuf_s[4][64];        // wave-private col gather
  float (*rs_area)[65] = rs_area_s[w];
  float* colbuf = colbuf_s[w];

  int z, bi, bj; const _Float16 *A, *B; const float *as, *bs;
  if (t < 2080)      { z = 0; tri_decode(t, bi, bj);        A = H1; B = H1; as = sq1; bs = sq1; }
  else if (t < 6176) { z = 1; int v = t - 2080; bi = v >> 6; bj = v & 63;
                                                            A = H1; B = H2; as = sq1; bs = sq2; }
  else               { z = 2; tri_decode(t - 6176, bi, bj); A = H2; B = H2; as = sq2; bs = sq2; }

  const f16x8* Af = reinterpret_cast<const f16x8*>(A);
  const f16x8* Bf = reinterpret_cast<const f16x8*>(B);

  float cb[4];
  #pragma unroll
  for (int ni = 0; ni < 4; ++ni) cb[ni] = 0.5f * bs[bj * 64 + ni * 16 + lr];

  float cpart[4] = {0.f, 0.f, 0.f, 0.f};
  float k2a = 0.f, k2b = 0.f;

  if ((z != 1) && (bi == bj))
    work_tile<true >(Af, Bf, as, cb, bi, bj, lane, lr, lg, rs_area, cpart, k2a, k2b);
  else
    work_tile<false>(Af, Bf, as, cb, bi, bj, lane, lr, lg, rs_area, cpart, k2a, k2b);

  float rsum = 0.f;
  #pragma unroll
  for (int j = 0; j < 16; ++j) rsum += rs_area[j][lane];   // conflict-free reads

  #pragma unroll
  for (int ni = 0; ni < 4; ++ni) {
    float cp = cpart[ni];
    cp += __shfl_xor(cp, 16);
    cp += __shfl_xor(cp, 32);
    if (lg == 0) colbuf[ni * 16 + lr] = cp;
  }
  const float cval = colbuf[lane];

  float* rowslab = slabs + (size_t)((z == 0) ? 0 : (z == 1) ? 1 : 3) * SLAB;
  rowslab[(size_t)bj * 4096 + bi * 64 + lane] = rsum;
  if (z == 1)
    slabs[(size_t)2 * SLAB + (size_t)bi * 4096 + bj * 64 + lane] = cval;
  else if (bi != bj)
    rowslab[(size_t)bi * 4096 + bj * 64 + lane] = cval;   // mirror (symmetry)

  float k2s = k2a + k2b;
  #pragma unroll
  for (int o = 32; o; o >>= 1) k2s += __shfl_xor(k2s, o);
  if (lane == 0) {
    const float wt = (z != 1 && bi != bj) ? 2.f : 1.f;
    bpart[t] = wt * k2s;
  }
}

// ---- stage A: per (chunk, slab) reduce: sum 64 slot-slabs, emit {sum^2, sum} ----
__global__ __launch_bounds__(256) void vdr_reduceA(const float* __restrict__ slabs,
                                                   double* __restrict__ partA) {
  const int j = blockIdx.y, tid = threadIdx.x;
  const int e = blockIdx.x * 256 + tid;
  const float* base = slabs + (size_t)j * SLAB + e;
  double s = 0.0;
  #pragma unroll
  for (int k = 0; k < 64; ++k) s += (double)base[(size_t)k * 4096];
  double sq = s * s, sm = s;
  #pragma unroll
  for (int o = 32; o; o >>= 1) { sq += __shfl_down(sq, o); sm += __shfl_down(sm, o); }
  __shared__ double sh[4][2];
  const int lane = tid & 63, wid = tid >> 6;
  if (lane == 0) { sh[wid][0] = sq; sh[wid][1] = sm; }
  __syncthreads();
  if (tid == 0) {
    partA[(size_t)(j * 16 + blockIdx.x) * 2 + 0] = sh[0][0] + sh[1][0] + sh[2][0] + sh[3][0];
    partA[(size_t)(j * 16 + blockIdx.x) * 2 + 1] = sh[0][1] + sh[1][1] + sh[2][1] + sh[3][1];
  }
}

// ---- stage B: combine partials + bpart, apply unbiased formula ----
__global__ __launch_bounds__(256) void vdr_reduceB(const double* __restrict__ partA,
                                                   const float* __restrict__ bpart,
                                                   float* __restrict__ out) {
  const int tid = threadIdx.x;
  __shared__ double ssq[4], ssum[4], s2sh[4][3];
  double s2[3] = {0.0, 0.0, 0.0};
  for (int i = tid; i < NTILES; i += 256) {
    const double v = (double)bpart[i];
    if (i < 2080) s2[0] += v; else if (i < 6176) s2[1] += v; else s2[2] += v;
  }
  #pragma unroll
  for (int o = 32; o; o >>= 1) {
    s2[0] += __shfl_down(s2[0], o);
    s2[1] += __shfl_down(s2[1], o);
    s2[2] += __shfl_down(s2[2], o);
  }
  const int lane = tid & 63, wid = tid >> 6;
  if (lane == 0) { s2sh[wid][0] = s2[0]; s2sh[wid][1] = s2[1]; s2sh[wid][2] = s2[2]; }
  if (tid < 64) {
    const int j = tid >> 4, c = tid & 15;
    double sq = partA[(size_t)(j * 16 + c) * 2 + 0];
    double sm = partA[(size_t)(j * 16 + c) * 2 + 1];
    #pragma unroll
    for (int o = 8; o; o >>= 1) { sq += __shfl_down(sq, o, 16); sm += __shfl_down(sm, o, 16); }
    if (c == 0) { ssq[j] = sq; ssum[j] = sm; }
  }
  __syncthreads();
  if (tid == 0) {
    const double S2XX = s2sh[0][0] + s2sh[1][0] + s2sh[2][0] + s2sh[3][0];
    const double S2XY = s2sh[0][1] + s2sh[1][1] + s2sh[2][1] + s2sh[3][1];
    const double S2YY = s2sh[0][2] + s2sh[1][2] + s2sh[2][2] + s2sh[3][2];
    const double inv = 1.0 / 4096.0;
    const double r0 = S2XX - 2.0 * ssq[0] * inv + ssum[0] * ssum[0] * inv * inv;
    const double r1 = S2XY - ssq[1] * inv - ssq[2] * inv + ssum[1] * ssum[1] * inv * inv;
    const double r2 = S2YY - 2.0 * ssq[3] * inv + ssum[3] * ssum[3] * inv * inv;
    const double mf = 4096.0;
    out[0] = (float)((r0 - mf) / ((mf - 1.0) * mf)
                   + (r2 - mf) / ((mf - 1.0) * mf)
                   - 2.0 * r1 / (mf * mf));
  }
}

extern "C" void kernel_launch(void* const* d_in, const int* in_sizes, int n_in,
                              void* d_out, int out_size, void* d_ws, size_t ws_size,
                              hipStream_t stream) {
  const float* X1 = (const float*)d_in[0];
  const float* X2 = (const float*)d_in[1];
  char* ws = (char*)d_ws;
  float* sq1      = (float*)(ws + OFF_SQ1);
  float* sq2      = (float*)(ws + OFF_SQ2);
  _Float16* H1    = (_Float16*)(ws + OFF_H1);
  _Float16* H2    = (_Float16*)(ws + OFF_H2);
  float* slabs    = (float*)(ws + OFF_SLABS);
  float* bpart    = (float*)(ws + OFF_BPART);
  double* partA   = (double*)(ws + OFF_PARTA);

  vdr_prep<<<512, 256, 0, stream>>>(X1, X2, H1, H2, sq1, sq2);
  vdr_main<<<2064, 256, 0, stream>>>(H1, H2, sq1, sq2, slabs, bpart);
  dim3 ga(16, 4);
  vdr_reduceA<<<ga, 256, 0, stream>>>(slabs, partA);
  vdr_reduceB<<<1, 256, 0, stream>>>(partA, bpart, (float*)d_out);
}

// Round 15
// 47.237 us; speedup vs baseline: 2.2261x; 1.0082x over previous
//
#include <hip/hip_runtime.h>

// VDR (Student-t kernel MMD variance) — fused, no K materialization.
// sum((K-rm-cm+t)^2) == sum(K^2) - sum(rowsum^2)/n - sum(colsum^2)/m + T^2/(mn)
// R1: killed S2 atomic. R2: killed all atomics. R3: tri symmetry.
// R7: fragment-contiguous H -> dense loads. R8/R10/R12 neutral. R13 VOID
// (forced launch_bounds -> allocator overshoot + 215MB spill; never coerce).
// R14: quarter-chunk (acc 16 regs) -> 51.0 -> 47.6us. L1 re-reads x4 did NOT
// hurt -> L1 BW not binding; register-limited TLP is. Gradient: acc32 neutral,
// acc16 +3.4us. R15: EIGHTH-CHUNK (16x32): MFMA region = acc[2](8)+a(4)+b(8);
// rp[4] row-partials accumulate across col-halves in regs. Target <=64 VGPR
// -> 8 waves/SIMD (m69 threshold). Everything else identical to R14.

typedef __attribute__((ext_vector_type(8))) _Float16 f16x8;
typedef __attribute__((ext_vector_type(4))) float f32x4;

#define LOG2G (-0.99304426f)  // log2(gamma(0.8)/(gamma(0.3)*sqrt(0.6)))
#define GAMMA_F 0.50241665f
#define NTILES 8256           // 2080 XX-tri + 4096 XY + 2080 YY (64x64 tiles)
#define SLAB (64 * 4096)

// workspace layout (bytes)
#define OFF_SQ1   0                       // float sq1[4096]
#define OFF_SQ2   16384                   // float sq2[4096]
#define OFF_H1    32768                   // _Float16 H1f[256][16][16][8]
#define OFF_H2    1081344                 // _Float16 H2f[256][16][16][8]
#define OFF_SLABS 2129920                 // float slabs[4][64][4096] {XX, XYr, XYc, YY}
#define OFF_BPART (2129920 + 4194304)     // float bpart[8256]
#define OFF_PARTA (OFF_BPART + 33024)     // double partA[4][16][2]

// ---- prep: fp32 -> f16, fragment-contiguous layout + squared row norms ----
__global__ __launch_bounds__(256) void vdr_prep(const float* __restrict__ X1,
                                                const float* __restrict__ X2,
                                                _Float16* __restrict__ H1,
                                                _Float16* __restrict__ H2,
                                                float* __restrict__ sq1,
                                                float* __restrict__ sq2) {
  const int tid = threadIdx.x;
  const int g = tid & 15;
  const int grow = blockIdx.x * 16 + (tid >> 4);   // 0..8191
  const float* X; _Float16* Hf; float* SQ; int row;
  if (grow < 4096) { X = X1; Hf = H1; SQ = sq1; row = grow; }
  else             { X = X2; Hf = H2; SQ = sq2; row = grow - 4096; }
  const float4* src = reinterpret_cast<const float4*>(X + (size_t)row * 128 + g * 8);
  const float4 v0 = src[0];
  const float4 v1 = src[1];
  f16x8 h;
  h[0] = (_Float16)v0.x; h[1] = (_Float16)v0.y; h[2] = (_Float16)v0.z; h[3] = (_Float16)v0.w;
  h[4] = (_Float16)v1.x; h[5] = (_Float16)v1.y; h[6] = (_Float16)v1.z; h[7] = (_Float16)v1.w;
  const int R = row >> 4;
  reinterpret_cast<f16x8*>(Hf)[(size_t)(R * 16 + g) * 16 + (row & 15)] = h;
  float s = v0.x * v0.x + v0.y * v0.y + v0.z * v0.z + v0.w * v0.w
          + v1.x * v1.x + v1.y * v1.y + v1.z * v1.z + v1.w * v1.w;
  #pragma unroll
  for (int o = 1; o < 16; o <<= 1) s += __shfl_xor(s, o);
  if (g == 0) SQ[row] = s;
}

// upper-triangle 64x64-tile decode: u in [0,2080) -> (bi, bj), bi<=bj
__device__ __forceinline__ void tri_decode(int u, int& bi, int& bj) {
  int b = (int)(64.5f - sqrtf(4160.25f - 2.0f * (float)u));
  if (b < 0) b = 0; if (b > 63) b = 63;
  while (b > 0 && (b * (129 - b)) / 2 > u) --b;
  while (b < 63 && ((b + 1) * (128 - b)) / 2 <= u) ++b;
  bi = b;
  bj = b + (u - (b * (129 - b)) / 2);
}

// ---- tile worker: 8 chunks of 16x32; minimal MFMA-region liveness ----
template<bool DG>
__device__ __forceinline__ void work_tile(const f16x8* __restrict__ Af,
                                          const f16x8* __restrict__ Bf,
                                          const float* __restrict__ as,
                                          const float* cb, int bi, int bj,
                                          int lane, int lr, int lg,
                                          float (*rs_area)[65],
                                          float* cpart, float& k2a, float& k2b) {
  for (int q = 0; q < 4; ++q) {
    const int rowb = q * 16;
    const float4 aq = *reinterpret_cast<const float4*>(as + bi * 64 + rowb + lg * 4);
    const float aqv[4] = {aq.x, aq.y, aq.z, aq.w};
    float rp[4] = {0.f, 0.f, 0.f, 0.f};     // row partials across both col-halves

    #pragma unroll
    for (int c = 0; c < 2; ++c) {
      f32x4 acc[2];
      #pragma unroll
      for (int n2 = 0; n2 < 2; ++n2)
        acc[n2] = (f32x4){0.f, 0.f, 0.f, 0.f};

      // MFMA: rows [q*16,+16) x cols [c*32,+32): only a(4)+b(8)+acc(8) live
      __builtin_amdgcn_s_setprio(1);
      #pragma unroll
      for (int ks = 0; ks < 4; ++ks) {
        const int fo = ks * 64 + lane;
        const f16x8 a = Af[(size_t)(bi * 4 + q) * 256 + fo];
        f16x8 b[2];
        #pragma unroll
        for (int n2 = 0; n2 < 2; ++n2)
          b[n2] = Bf[(size_t)(bj * 4 + c * 2 + n2) * 256 + fo];
        #pragma unroll
        for (int n2 = 0; n2 < 2; ++n2)
          acc[n2] = __builtin_amdgcn_mfma_f32_16x16x32_f16(a, b[n2], acc[n2], 0, 0, 0);
      }
      __builtin_amdgcn_s_setprio(0);

      // epilogue for this 16x32 chunk (acc dies here)
      #pragma unroll
      for (int rg = 0; rg < 4; ++rg) {
        const float pre = __builtin_fmaf(0.5f, aqv[rg], 1.0f);
        float e[2];
        #pragma unroll
        for (int n2 = 0; n2 < 2; ++n2)
          e[n2] = (pre + cb[c * 2 + n2]) - acc[n2][rg];
        #pragma unroll
        for (int n2 = 0; n2 < 2; ++n2)
          e[n2] = __builtin_amdgcn_logf(e[n2]);
        #pragma unroll
        for (int n2 = 0; n2 < 2; ++n2)
          e[n2] = __builtin_amdgcn_exp2f(__builtin_fmaf(-0.8f, e[n2], LOG2G));
        if (DG) {
          #pragma unroll
          for (int n2 = 0; n2 < 2; ++n2)
            if ((rowb + lg * 4 + rg) == ((c * 2 + n2) * 16 + lr)) e[n2] = GAMMA_F;
        }
        rp[rg] += e[0] + e[1];
        cpart[c * 2 + 0] += e[0];
        cpart[c * 2 + 1] += e[1];
        k2a = __builtin_fmaf(e[0], e[0], k2a);
        k2b = __builtin_fmaf(e[1], e[1], k2b);
      }
    }
    #pragma unroll
    for (int rg = 0; rg < 4; ++rg)
      rs_area[lr][rowb + lg * 4 + rg] = rp[rg];
  }
}

// ---- main: one 64x64 tile per WAVE; no barriers; low natural VGPR ----
__global__ __launch_bounds__(256) void vdr_main(const _Float16* __restrict__ H1,
                                                const _Float16* __restrict__ H2,
                                                const float* __restrict__ sq1,
                                                const float* __restrict__ sq2,
                                                float* __restrict__ slabs,
                                                float* __restrict__ bpart) {
  const int w = threadIdx.x >> 6, lane = threadIdx.x & 63;
  const int lr = lane & 15, lg = lane >> 4;
  const int t = blockIdx.x * 4 + w;

  __shared__ float rs_area_s[4][16][65];   // wave-private transpose area
  __shared__ float colbuf_s[4][64];        // wave-private col gather
  float (*rs_area)[65] = rs_area_s[w];
  float* colbuf = colbuf_s[w];

  int z, bi, bj; const _Float16 *A, *B; const float *as, *bs;
  if (t < 2080)      { z = 0; tri_decode(t, bi, bj);        A = H1; B = H1; as = sq1; bs = sq1; }
  else if (t < 6176) { z = 1; int v = t - 2080; bi = v >> 6; bj = v & 63;
                                                            A = H1; B = H2; as = sq1; bs = sq2; }
  else               { z = 2; tri_decode(t - 6176, bi, bj); A = H2; B = H2; as = sq2; bs = sq2; }

  const f16x8* Af = reinterpret_cast<const f16x8*>(A);
  const f16x8* Bf = reinterpret_cast<const f16x8*>(B);

  float cb[4];
  #pragma unroll
  for (int ni = 0; ni < 4; ++ni) cb[ni] = 0.5f * bs[bj * 64 + ni * 16 + lr];

  float cpart[4] = {0.f, 0.f, 0.f, 0.f};
  float k2a = 0.f, k2b = 0.f;

  if ((z != 1) && (bi == bj))
    work_tile<true >(Af, Bf, as, cb, bi, bj, lane, lr, lg, rs_area, cpart, k2a, k2b);
  else
    work_tile<false>(Af, Bf, as, cb, bi, bj, lane, lr, lg, rs_area, cpart, k2a, k2b);

  float rsum = 0.f;
  #pragma unroll
  for (int j = 0; j < 16; ++j) rsum += rs_area[j][lane];   // conflict-free reads

  #pragma unroll
  for (int ni = 0; ni < 4; ++ni) {
    float cp = cpart[ni];
    cp += __shfl_xor(cp, 16);
    cp += __shfl_xor(cp, 32);
    if (lg == 0) colbuf[ni * 16 + lr] = cp;
  }
  const float cval = colbuf[lane];

  float* rowslab = slabs + (size_t)((z == 0) ? 0 : (z == 1) ? 1 : 3) * SLAB;
  rowslab[(size_t)bj * 4096 + bi * 64 + lane] = rsum;
  if (z == 1)
    slabs[(size_t)2 * SLAB + (size_t)bi * 4096 + bj * 64 + lane] = cval;
  else if (bi != bj)
    rowslab[(size_t)bi * 4096 + bj * 64 + lane] = cval;   // mirror (symmetry)

  float k2s = k2a + k2b;
  #pragma unroll
  for (int o = 32; o; o >>= 1) k2s += __shfl_xor(k2s, o);
  if (lane == 0) {
    const float wt = (z != 1 && bi != bj) ? 2.f : 1.f;
    bpart[t] = wt * k2s;
  }
}

// ---- stage A: per (chunk, slab) reduce: sum 64 slot-slabs, emit {sum^2, sum} ----
__global__ __launch_bounds__(256) void vdr_reduceA(const float* __restrict__ slabs,
                                                   double* __restrict__ partA) {
  const int j = blockIdx.y, tid = threadIdx.x;
  const int e = blockIdx.x * 256 + tid;
  const float* base = slabs + (size_t)j * SLAB + e;
  double s = 0.0;
  #pragma unroll
  for (int k = 0; k < 64; ++k) s += (double)base[(size_t)k * 4096];
  double sq = s * s, sm = s;
  #pragma unroll
  for (int o = 32; o; o >>= 1) { sq += __shfl_down(sq, o); sm += __shfl_down(sm, o); }
  __shared__ double sh[4][2];
  const int lane = tid & 63, wid = tid >> 6;
  if (lane == 0) { sh[wid][0] = sq; sh[wid][1] = sm; }
  __syncthreads();
  if (tid == 0) {
    partA[(size_t)(j * 16 + blockIdx.x) * 2 + 0] = sh[0][0] + sh[1][0] + sh[2][0] + sh[3][0];
    partA[(size_t)(j * 16 + blockIdx.x) * 2 + 1] = sh[0][1] + sh[1][1] + sh[2][1] + sh[3][1];
  }
}

// ---- stage B: combine partials + bpart, apply unbiased formula ----
__global__ __launch_bounds__(256) void vdr_reduceB(const double* __restrict__ partA,
                                                   const float* __restrict__ bpart,
                                                   float* __restrict__ out) {
  const int tid = threadIdx.x;
  __shared__ double ssq[4], ssum[4], s2sh[4][3];
  double s2[3] = {0.0, 0.0, 0.0};
  for (int i = tid; i < NTILES; i += 256) {
    const double v = (double)bpart[i];
    if (i < 2080) s2[0] += v; else if (i < 6176) s2[1] += v; else s2[2] += v;
  }
  #pragma unroll
  for (int o = 32; o; o >>= 1) {
    s2[0] += __shfl_down(s2[0], o);
    s2[1] += __shfl_down(s2[1], o);
    s2[2] += __shfl_down(s2[2], o);
  }
  const int lane = tid & 63, wid = tid >> 6;
  if (lane == 0) { s2sh[wid][0] = s2[0]; s2sh[wid][1] = s2[1]; s2sh[wid][2] = s2[2]; }
  if (tid < 64) {
    const int j = tid >> 4, c = tid & 15;
    double sq = partA[(size_t)(j * 16 + c) * 2 + 0];
    double sm = partA[(size_t)(j * 16 + c) * 2 + 1];
    #pragma unroll
    for (int o = 8; o; o >>= 1) { sq += __shfl_down(sq, o, 16); sm += __shfl_down(sm, o, 16); }
    if (c == 0) { ssq[j] = sq; ssum[j] = sm; }
  }
  __syncthreads();
  if (tid == 0) {
    const double S2XX = s2sh[0][0] + s2sh[1][0] + s2sh[2][0] + s2sh[3][0];
    const double S2XY = s2sh[0][1] + s2sh[1][1] + s2sh[2][1] + s2sh[3][1];
    const double S2YY = s2sh[0][2] + s2sh[1][2] + s2sh[2][2] + s2sh[3][2];
    const double inv = 1.0 / 4096.0;
    const double r0 = S2XX - 2.0 * ssq[0] * inv + ssum[0] * ssum[0] * inv * inv;
    const double r1 = S2XY - ssq[1] * inv - ssq[2] * inv + ssum[1] * ssum[1] * inv * inv;
    const double r2 = S2YY - 2.0 * ssq[3] * inv + ssum[3] * ssum[3] * inv * inv;
    const double mf = 4096.0;
    out[0] = (float)((r0 - mf) / ((mf - 1.0) * mf)
                   + (r2 - mf) / ((mf - 1.0) * mf)
                   - 2.0 * r1 / (mf * mf));
  }
}

extern "C" void kernel_launch(void* const* d_in, const int* in_sizes, int n_in,
                              void* d_out, int out_size, void* d_ws, size_t ws_size,
                              hipStream_t stream) {
  const float* X1 = (const float*)d_in[0];
  const float* X2 = (const float*)d_in[1];
  char* ws = (char*)d_ws;
  float* sq1      = (float*)(ws + OFF_SQ1);
  float* sq2      = (float*)(ws + OFF_SQ2);
  _Float16* H1    = (_Float16*)(ws + OFF_H1);
  _Float16* H2    = (_Float16*)(ws + OFF_H2);
  float* slabs    = (float*)(ws + OFF_SLABS);
  float* bpart    = (float*)(ws + OFF_BPART);
  double* partA   = (double*)(ws + OFF_PARTA);

  vdr_prep<<<512, 256, 0, stream>>>(X1, X2, H1, H2, sq1, sq2);
  vdr_main<<<2064, 256, 0, stream>>>(H1, H2, sq1, sq2, slabs, bpart);
  dim3 ga(16, 4);
  vdr_reduceA<<<ga, 256, 0, stream>>>(slabs, partA);
  vdr_reduceB<<<1, 256, 0, stream>>>(partA, bpart, (float*)d_out);
}